// Round 14
// baseline (209.371 us; speedup 1.0000x reference)
//
#include <hip/hip_runtime.h>
#include <math.h>

#define Bb 2
#define Nn 2048
#define Dd 1024
#define Hh 16
#define HD 64
#define KVB 128
// M = B*N = 4096 rows

typedef __attribute__((ext_vector_type(8))) short short8;    // 8 bf16 = 4 VGPR (MFMA A/B frag)
typedef __attribute__((ext_vector_type(4))) short short4v;   // 4 bf16 = 2 VGPR (K=16 MFMA frag)
typedef __attribute__((ext_vector_type(4))) float floatx4;   // MFMA C/D frag

// float -> bf16 bits, round-to-nearest-even (values are finite here)
__device__ __forceinline__ short f2bf(float x) {
    unsigned u = __float_as_uint(x);
    u += 0x7fffu + ((u >> 16) & 1u);
    return (short)(u >> 16);
}

// K=16 bf16 MFMA: A-frag layout A[m=lane&15][k=quad*4+j] == C/D layout of the
// S-MFMA -> P feeds PV directly from accumulator registers (no LDS roundtrip).
#if defined(__has_builtin)
#  if __has_builtin(__builtin_amdgcn_mfma_f32_16x16x16bf16_1k)
#    define MFMA16(a, b, c) __builtin_amdgcn_mfma_f32_16x16x16bf16_1k(a, b, c, 0, 0, 0)
#  endif
#endif
#ifndef MFMA16
static __device__ __forceinline__ floatx4 mfma16_asm(short4v a, short4v b, floatx4 c) {
    asm volatile("v_mfma_f32_16x16x16_bf16 %0, %1, %2, %0" : "+v"(c) : "v"(a), "v"(b));
    return c;
}
#  define MFMA16(a, b, c) mfma16_asm(a, b, c)
#endif

// exp2 without the llvm.exp2 denormal-range fixup: scores are bounded
// (|x| < ~40 after LN + QSCALE), so the bare v_exp_f32 is exact here.
// Builtin (not inline asm!) so the compiler inserts TRANS-op wait states.
__device__ __forceinline__ float fexp2(float x) {
#if defined(__has_builtin)
#  if __has_builtin(__builtin_amdgcn_exp2f)
    return __builtin_amdgcn_exp2f(x);
#  else
    return exp2f(x);
#  endif
#else
    return exp2f(x);
#endif
}

// async 16B global -> LDS (DMA; LDS dest is wave-uniform base + lane*16)
__device__ __forceinline__ void gload16(const void* g, void* l) {
    __builtin_amdgcn_global_load_lds(
        (const __attribute__((address_space(1))) unsigned int*)g,
        (__attribute__((address_space(3))) unsigned int*)l,
        16, 0, 0);
}

#define QSCALE 0.18033688011112042f   // 0.125 * log2(e), pre-applied to Q

// ---------------------------------------------------------------------------
// One-shot bf16 cast of x and the four weight matrices. Tight 1D grid
// (8192 blocks exactly). x: blocks [0,4096); weights: 1024 blocks each.
// ---------------------------------------------------------------------------
__global__ __launch_bounds__(256) void cast_all(
    const float* __restrict__ x,
    const float* __restrict__ Wq, const float* __restrict__ Wk,
    const float* __restrict__ Wv, const float* __restrict__ Wp,
    short* __restrict__ xh, short* __restrict__ Wqh, short* __restrict__ Wkh,
    short* __restrict__ Wvh, short* __restrict__ Wph)
{
    const int bid = blockIdx.x;
    const float* src; short* dst; int i;
    if (bid < 4096) {
        src = x; dst = xh;
        i = bid * 256 + threadIdx.x;
    } else {
        const int wsel = (bid - 4096) >> 10;          // 0..3
        switch (wsel) {
            case 0:  src = Wq; dst = Wqh; break;
            case 1:  src = Wk; dst = Wkh; break;
            case 2:  src = Wv; dst = Wvh; break;
            default: src = Wp; dst = Wph; break;
        }
        i = ((bid - 4096) & 1023) * 256 + threadIdx.x;
    }
    float4 v = ((const float4*)src)[i];
    short4v o;
    o.x = f2bf(v.x); o.y = f2bf(v.y); o.z = f2bf(v.z); o.w = f2bf(v.w);
    ((short4v*)dst)[i] = o;
}

// ---------------------------------------------------------------------------
// Fused QKV GEMM with per-head LayerNorm epilogue. Verified R7/R9 twin-buffer
// BK=64 structure + R14 XCD panel-swizzle: qkv is the largest kernel (~66us,
// MfmaUtil ~14% -- stage latency exposed at each barrier). The 32 blocks
// sharing one 2MB W panel were round-robined over 8 XCD L2s; bijective remap
// (768 = 8 x 96 = 8 x 3 panels x 32 blocks) puts each (by,z) panel-group on
// ONE XCD: 3 panels x 2MB <= 4MB L2 -> staging loads become L2 hits (~200cy
// vs ~900), directly shrinking the barrier-exposed stall. (Mapping convention
// validated by flash's swizzle: FETCH 73.7 -> 12.8MB.)
// ---------------------------------------------------------------------------
__global__ __launch_bounds__(256) void qkv_ln_gemm(
    const short* __restrict__ xh,
    const short* __restrict__ Wqh, const short* __restrict__ Wkh,
    const short* __restrict__ Wvh,
    const float* __restrict__ bq, const float* __restrict__ bk,
    const float* __restrict__ bv,
    const float* __restrict__ qg, const float* __restrict__ qb,
    const float* __restrict__ kg, const float* __restrict__ kb,
    short* __restrict__ Qh, short* __restrict__ Kh, short* __restrict__ Vt)
{
    // ---- XCD panel-swizzle (bijective on 0..767) ----
    const int lin = blockIdx.x + (blockIdx.y << 5) + (blockIdx.z << 8); // gx=32, gy=8
    const int xcd = lin & 7;            // dispatcher round-robins linear id % 8
    const int i8  = lin >> 3;           // 0..95 within this XCD
    const int p   = xcd * 3 + (i8 >> 5);// panel 0..23 = (z,by); 3 panels/XCD
    const int bx  = i8 & 31;            // 0..31 row-block within panel
    const int by  = p & 7;
    const int z   = p >> 3;             // 0..2

    const short* A; const short* W;
    int rowBase, colBase, Nc;
    if (z < 2) { A = xh;  W = z ? Wkh : Wqh;
                 rowBase = bx * 128; colBase = by * 128; Nc = Dd; }
    else       { A = Wvh; W = xh;
                 rowBase = by * 128; colBase = bx * 128; Nc = Bb * Nn; }

    __shared__ __align__(16) short As0[128 * 32];
    __shared__ __align__(16) short As1[128 * 32];
    __shared__ __align__(16) short Ws0[128 * 32];
    __shared__ __align__(16) short Ws1[128 * 32];

    const int t    = threadIdx.x;
    const int w    = t >> 6;
    const int lane = t & 63;
    const int quad = lane >> 4;
    const int l15  = lane & 15;
    const int wy   = w >> 1;
    const int wx   = w & 1;

    const int r0 = t >> 2;
    const int kg4 = (t & 3) * 8;
    const short* aP = A + (size_t)(rowBase + r0) * Dd + kg4;
    const short* wP = W + (size_t)(colBase + r0) * Dd + kg4;
    const size_t rowskip = (size_t)64 * Dd;

    floatx4 acc[4][4];
    #pragma unroll
    for (int mi = 0; mi < 4; ++mi)
        #pragma unroll
        for (int ni = 0; ni < 4; ++ni)
            acc[mi][ni] = (floatx4){0.f, 0.f, 0.f, 0.f};

    for (int k0 = 0; k0 < Dd; k0 += 64) {
        gload16(aP,                &As0[t * 8]);
        gload16(aP + rowskip,      &As0[(t + 256) * 8]);
        gload16(aP + 32,           &As1[t * 8]);
        gload16(aP + rowskip + 32, &As1[(t + 256) * 8]);
        gload16(wP,                &Ws0[t * 8]);
        gload16(wP + rowskip,      &Ws0[(t + 256) * 8]);
        gload16(wP + 32,           &Ws1[t * 8]);
        gload16(wP + rowskip + 32, &Ws1[(t + 256) * 8]);
        aP += 64; wP += 64;
        __syncthreads();   // drains vmcnt -> staged tiles visible

        #pragma unroll
        for (int ks = 0; ks < 2; ++ks) {
            const short* Ab = ks ? As1 : As0;
            const short* Wb = ks ? Ws1 : Ws0;
            short8 af[4], bfr[4];
            #pragma unroll
            for (int i = 0; i < 4; ++i) {
                af[i]  = *(const short8*)&Ab[(wy * 64 + i * 16 + l15) * 32 + quad * 8];
                bfr[i] = *(const short8*)&Wb[(wx * 64 + i * 16 + l15) * 32 + quad * 8];
            }
            #pragma unroll
            for (int mi = 0; mi < 4; ++mi)
                #pragma unroll
                for (int ni = 0; ni < 4; ++ni)
                    acc[mi][ni] = __builtin_amdgcn_mfma_f32_16x16x32_bf16(
                        af[mi], bfr[ni], acc[mi][ni], 0, 0, 0);
        }
        __syncthreads();
    }

    if (z == 2) {
        #pragma unroll
        for (int mi = 0; mi < 4; ++mi) {
            #pragma unroll
            for (int r = 0; r < 4; ++r) {
                const size_t row = rowBase + wy * 64 + mi * 16 + quad * 4 + r;
                const float brv = bv[row];
                #pragma unroll
                for (int ni = 0; ni < 4; ++ni) {
                    const int col = colBase + wx * 64 + ni * 16 + l15;
                    Vt[row * (size_t)Nc + col] = f2bf(acc[mi][ni][r] + brv);
                }
            }
        }
    } else {
        const float* bias = z ? bk : bq;
        const float* gam  = z ? kg : qg;
        const float* bet  = z ? kb : qb;
        const float oscale = z ? 1.0f : QSCALE;
        short* out = z ? Kh : Qh;
        float bcol[4], g4[4], be4[4];
        #pragma unroll
        for (int ni = 0; ni < 4; ++ni) {
            const int ch = ni * 16 + l15;
            bcol[ni] = bias[colBase + wx * 64 + ch];
            g4[ni]   = gam[ch];
            be4[ni]  = bet[ch];
        }
        #pragma unroll
        for (int mi = 0; mi < 4; ++mi) {
            #pragma unroll
            for (int r = 0; r < 4; ++r) {
                const size_t row = rowBase + wy * 64 + mi * 16 + quad * 4 + r;
                float v[4], s = 0.f, s2 = 0.f;
                #pragma unroll
                for (int ni = 0; ni < 4; ++ni) {
                    v[ni] = acc[mi][ni][r] + bcol[ni];
                    s += v[ni]; s2 += v[ni] * v[ni];
                }
                #pragma unroll
                for (int d = 1; d < 16; d <<= 1) {
                    s  += __shfl_xor(s,  d, 16);
                    s2 += __shfl_xor(s2, d, 16);
                }
                const float mean = s * (1.0f / 64.0f);
                const float var  = s2 * (1.0f / 64.0f) - mean * mean;   // biased (jnp.var)
                const float rr   = rsqrtf(var + 1e-5f);
                #pragma unroll
                for (int ni = 0; ni < 4; ++ni) {
                    const int col = colBase + wx * 64 + ni * 16 + l15;
                    out[row * (size_t)Dd + col] =
                        f2bf(((v[ni] - mean) * rr * g4[ni] + be4[ni]) * oscale);
                }
            }
        }
    }
}

// ---------------------------------------------------------------------------
// Output projection GEMM. Verified R7/R9 form: BK=64 twin buffers,
// 128x64 tile, 512 blocks = 2/CU. (Ping-pong measured -6us here in R12.)
// ---------------------------------------------------------------------------
__global__ __launch_bounds__(256) void gemm_mfma(
    const short* __restrict__ A, const short* __restrict__ W,
    const float* __restrict__ bias, float* __restrict__ Cf,
    int M, int K, int Nc)
{
    __shared__ __align__(16) short As0[128 * 32];   // 8 KB
    __shared__ __align__(16) short As1[128 * 32];   // 8 KB
    __shared__ __align__(16) short Ws0[64 * 32];    // 4 KB
    __shared__ __align__(16) short Ws1[64 * 32];    // 4 KB

    const int t    = threadIdx.x;
    const int w    = t >> 6;
    const int lane = t & 63;
    const int quad = lane >> 4;
    const int l15  = lane & 15;
    const int wy   = w >> 1;
    const int wx   = w & 1;
    const int rowBase = blockIdx.y * 128;
    const int colBase = blockIdx.x * 64;

    const int r0 = t >> 2;          // 0..63
    const int kg4 = (t & 3) * 8;
    const short* aP = A + (size_t)(rowBase + r0) * K + kg4;
    const short* wP = W + (size_t)(colBase + r0) * K + kg4;
    const size_t rowskip = (size_t)64 * K;

    floatx4 acc[4][2];
    #pragma unroll
    for (int mi = 0; mi < 4; ++mi)
        #pragma unroll
        for (int ni = 0; ni < 2; ++ni)
            acc[mi][ni] = (floatx4){0.f, 0.f, 0.f, 0.f};

    for (int k0 = 0; k0 < K; k0 += 64) {
        gload16(aP,                &As0[t * 8]);
        gload16(aP + rowskip,      &As0[(t + 256) * 8]);
        gload16(aP + 32,           &As1[t * 8]);
        gload16(aP + rowskip + 32, &As1[(t + 256) * 8]);
        gload16(wP,                &Ws0[t * 8]);
        gload16(wP + 32,           &Ws1[t * 8]);
        aP += 64; wP += 64;
        __syncthreads();

        #pragma unroll
        for (int ks = 0; ks < 2; ++ks) {
            const short* Ab = ks ? As1 : As0;
            const short* Wb = ks ? Ws1 : Ws0;
            short8 af[4], bfr[2];
            #pragma unroll
            for (int i = 0; i < 4; ++i)
                af[i]  = *(const short8*)&Ab[(wy * 64 + i * 16 + l15) * 32 + quad * 8];
            #pragma unroll
            for (int i = 0; i < 2; ++i)
                bfr[i] = *(const short8*)&Wb[(wx * 32 + i * 16 + l15) * 32 + quad * 8];
            #pragma unroll
            for (int mi = 0; mi < 4; ++mi)
                #pragma unroll
                for (int ni = 0; ni < 2; ++ni)
                    acc[mi][ni] = __builtin_amdgcn_mfma_f32_16x16x32_bf16(
                        af[mi], bfr[ni], acc[mi][ni], 0, 0, 0);
        }
        __syncthreads();
    }

    #pragma unroll
    for (int mi = 0; mi < 4; ++mi) {
        #pragma unroll
        for (int r = 0; r < 4; ++r) {
            const size_t row = rowBase + wy * 64 + mi * 16 + quad * 4 + r;
            #pragma unroll
            for (int ni = 0; ni < 2; ++ni) {
                const int col = colBase + wx * 32 + ni * 16 + l15;
                Cf[row * Nc + col] = acc[mi][ni][r] + bias[col];
            }
        }
    }
}

// ---------------------------------------------------------------------------
// Flash attention, bf16 MFMA, static-max softmax. Unchanged from verified R9
// (52.7us): KVB=128, 512 threads, XCD group-swizzle (FETCH 73.7->12.8MB),
// builtin exp2, setprio, conflict-free K/V LDS strides. Residual
// SQ_LDS_BANK_CONFLICT = 2^22 exactly = benign 2-way alias on K b128 reads
// (l15 vs l15+8), measured ~free (m136).
// ---------------------------------------------------------------------------
__global__ __launch_bounds__(512, 4) void flash_mfma(
    const short* __restrict__ Qh, const short* __restrict__ Kh,
    const short* __restrict__ Vt, short* __restrict__ ctx)
{
    // ---- XCD group-swizzle (bijective on 0..511) ----
    const int lin = blockIdx.x + (blockIdx.y << 4) + (blockIdx.z << 8);
    const int xcd = lin & 7;          // dispatcher round-robins linear id % 8
    const int ixc = lin >> 3;         // 0..63 within this XCD
    const int grp = xcd * 4 + (ixc >> 4);   // 0..31 = (h,b) group, 4 per XCD
    const int qt  = ixc & 15;         // 128-query tile
    const int h   = grp & 15;
    const int b   = grp >> 4;

    const int t    = threadIdx.x;   // 0..511
    const int w    = t >> 6;        // wave 0..7
    const int lane = t & 63;
    const int quad = lane >> 4;
    const int l15  = lane & 15;

    __shared__ __align__(16) short Ksh[KVB][72];   // [key][d]  18432B (stride 144B: clean b128)
    __shared__ __align__(16) short Vsh[64][140];   // [ch][key] 17920B (stride 280B = 70 dw == 6 mod 32: clean b64)

    const size_t bhead = (size_t)b * Nn * Dd + (size_t)h * HD;

    // Q B-frags: one 16-query set per wave, held in registers for all k-tiles
    short8 qf[2];
    {
        const short* qp = Qh + bhead
            + (size_t)(qt * 128 + w * 16 + l15) * Dd + quad * 8;
        qf[0] = *(const short8*)qp;
        qf[1] = *(const short8*)(qp + 32);
    }

    floatx4 accO[4], accL;
    #pragma unroll
    for (int n = 0; n < 4; ++n) accO[n] = (floatx4){0.f, 0.f, 0.f, 0.f};
    accL = (floatx4){0.f, 0.f, 0.f, 0.f};
    short4v ones;
    ones[0] = ones[1] = ones[2] = ones[3] = (short)0x3F80;   // bf16 1.0

    // staging: thread t owns K rows {s3, s3+64} (d-chunk skg) and V channel s3
    // (key chunks {skg, skg+64}); chunk rotated per row to spread banks.
    const int s3  = t >> 3;                   // 0..63
    const int c3  = ((t & 7) + (s3 & 7)) & 7;
    const int skg = c3 * 8;
    const short* kP = Kh + bhead + (size_t)s3 * Dd + skg;
    const short* vP = Vt + (size_t)(h * 64 + s3) * (size_t)(Bb * Nn) + (size_t)b * Nn + skg;

    // prefetch tile 0 into registers
    short8 kr0 = *(const short8*)kP;
    short8 kr1 = *(const short8*)(kP + (size_t)64 * Dd);
    short8 vr0 = *(const short8*)vP;
    short8 vr1 = *(const short8*)(vP + 64);

    for (int k0 = 0; k0 < Nn; k0 += KVB) {
        // ---- write prefetched tile to LDS ----
        *(short8*)&Ksh[s3][skg]      = kr0;
        *(short8*)&Ksh[s3 + 64][skg] = kr1;
        {   // V rows are 8B-aligned (stride 280B): write as b64 halves
            union { short8 v8; short4v v4[2]; } a0, a1;
            a0.v8 = vr0; a1.v8 = vr1;
            *(short4v*)&Vsh[s3][skg]      = a0.v4[0];
            *(short4v*)&Vsh[s3][skg + 4]  = a0.v4[1];
            *(short4v*)&Vsh[s3][skg + 64] = a1.v4[0];
            *(short4v*)&Vsh[s3][skg + 68] = a1.v4[1];
        }
        __syncthreads();   // staged tile visible to all waves

        // ---- issue next tile's global loads (hidden behind compute) ----
        kP += (size_t)KVB * Dd; vP += KVB;   // last iter strays into d_ws (safe, unused)
        kr0 = *(const short8*)kP;
        kr1 = *(const short8*)(kP + (size_t)64 * Dd);
        vr0 = *(const short8*)vP;
        vr1 = *(const short8*)(vP + 64);

        // ---- per 16-key subtile: S^T = K Q^T -> exp2 -> pack -> l, O += P V
        __builtin_amdgcn_s_setprio(1);
        #pragma unroll
        for (int n = 0; n < KVB / 16; ++n) {
            short8 kf0 = *(const short8*)&Ksh[n * 16 + l15][quad * 8];
            short8 kf1 = *(const short8*)&Ksh[n * 16 + l15][32 + quad * 8];
            floatx4 zz = (floatx4){0.f, 0.f, 0.f, 0.f};
            zz = __builtin_amdgcn_mfma_f32_16x16x32_bf16(kf0, qf[0], zz, 0, 0, 0);
            zz = __builtin_amdgcn_mfma_f32_16x16x32_bf16(kf1, qf[1], zz, 0, 0, 0);

            const unsigned u0 = __float_as_uint(fexp2(zz[0]));
            const unsigned u1 = __float_as_uint(fexp2(zz[1]));
            const unsigned u2 = __float_as_uint(fexp2(zz[2]));
            const unsigned u3 = __float_as_uint(fexp2(zz[3]));
            union { uint2 u; short4v s; } pk;
            pk.u.x = __builtin_amdgcn_perm(u1, u0, 0x07060302u);  // trunc-bf16 pair
            pk.u.y = __builtin_amdgcn_perm(u3, u2, 0x07060302u);
            accL = MFMA16(pk.s, ones, accL);   // l += P·1 (matrix pipe)

            #pragma unroll
            for (int c = 0; c < 4; ++c) {   // channel subtile
                const short4v vb =
                    *(const short4v*)&Vsh[c * 16 + l15][n * 16 + quad * 4];
                accO[c] = MFMA16(pk.s, vb, accO[c]);
            }
        }
        __builtin_amdgcn_s_setprio(0);
        __syncthreads();   // protect Ksh/Vsh before next tile's LDS write
    }

    // ---- epilogue: accL[r] IS this lane's query's l -> normalize ----
    #pragma unroll
    for (int r = 0; r < 4; ++r) {
        const float lr = 1.0f / accL[r];
        short* dst = ctx + (size_t)((b * Nn) + qt * 128 + w * 16
                                    + quad * 4 + r) * Dd + h * HD + l15;
        #pragma unroll
        for (int n = 0; n < 4; ++n) dst[n * 16] = f2bf(accO[n][r] * lr);
    }
}

// ---------------------------------------------------------------------------
extern "C" void kernel_launch(void* const* d_in, const int* in_sizes, int n_in,
                              void* d_out, int out_size, void* d_ws, size_t ws_size,
                              hipStream_t stream) {
    const float* x   = (const float*)d_in[0];
    const float* Wq  = (const float*)d_in[1];
    const float* bq  = (const float*)d_in[2];
    const float* Wk  = (const float*)d_in[3];
    const float* bk  = (const float*)d_in[4];
    const float* Wv  = (const float*)d_in[5];
    const float* bv  = (const float*)d_in[6];
    const float* Wp  = (const float*)d_in[7];
    const float* bp  = (const float*)d_in[8];
    const float* qg  = (const float*)d_in[9];
    const float* qb  = (const float*)d_in[10];
    const float* kg  = (const float*)d_in[11];
    const float* kb  = (const float*)d_in[12];
    float* out = (float*)d_out;

    const size_t S = (size_t)Bb * Nn * Dd;   // 4,194,304 elements
    short* wsb = (short*)d_ws;               // all-bf16 workspace (48 MB)
    short* xh   = wsb;                       // [0,  8MB)
    short* Vt   = wsb + S;                   // [8, 16MB)  V^T [1024][4096]
    short* Kh   = wsb + 2 * S;               // [16,24MB)
    short* Qh   = wsb + 3 * S;               // [24,32MB)
    short* ctxh = wsb + 4 * S;               // [32,40MB)
    short* Wqh  = wsb + 5 * S;               // [40,48MB) 4 weights, 2MB each
    short* Wkh  = Wqh + Dd * Dd;
    short* Wvh  = Wkh + Dd * Dd;
    short* Wph  = Wvh + Dd * Dd;

    const int M = Bb * Nn;                   // 4096

    cast_all<<<dim3(8192), 256, 0, stream>>>(x, Wq, Wk, Wv, Wp,
                                             xh, Wqh, Wkh, Wvh, Wph);

    // fused QKV projections + per-head LN (Q,K; Q pre-scaled) + transposed V
    qkv_ln_gemm<<<dim3(M / 128, Dd / 128, 3), 256, 0, stream>>>(
        xh, Wqh, Wkh, Wvh, bq, bk, bv, qg, qb, kg, kb, Qh, Kh, Vt);

    flash_mfma<<<dim3(Nn / 128, Hh, Bb), 512, 0, stream>>>(Qh, Kh, Vt, ctxh);

    // output projection (bf16 MFMA, fp32 out + bias): twin-buffer BK=64
    gemm_mfma<<<dim3(Dd / 64, M / 128, 1), 256, 0, stream>>>(
        ctxh, Wph, bp, out, M, Dd, Dd);
}

// Round 15
// 202.957 us; speedup vs baseline: 1.0316x; 1.0316x over previous
//
#include <hip/hip_runtime.h>
#include <math.h>

#define Bb 2
#define Nn 2048
#define Dd 1024
#define Hh 16
#define HD 64
#define KVB 128
// M = B*N = 4096 rows

typedef __attribute__((ext_vector_type(8))) short short8;    // 8 bf16 = 4 VGPR (MFMA A/B frag)
typedef __attribute__((ext_vector_type(4))) short short4v;   // 4 bf16 = 2 VGPR (K=16 MFMA frag)
typedef __attribute__((ext_vector_type(4))) float floatx4;   // MFMA C/D frag

// float -> bf16 bits, round-to-nearest-even (values are finite here)
__device__ __forceinline__ short f2bf(float x) {
    unsigned u = __float_as_uint(x);
    u += 0x7fffu + ((u >> 16) & 1u);
    return (short)(u >> 16);
}

// K=16 bf16 MFMA: A-frag layout A[m=lane&15][k=quad*4+j] == C/D layout of the
// S-MFMA -> P feeds PV directly from accumulator registers (no LDS roundtrip).
#if defined(__has_builtin)
#  if __has_builtin(__builtin_amdgcn_mfma_f32_16x16x16bf16_1k)
#    define MFMA16(a, b, c) __builtin_amdgcn_mfma_f32_16x16x16bf16_1k(a, b, c, 0, 0, 0)
#  endif
#endif
#ifndef MFMA16
static __device__ __forceinline__ floatx4 mfma16_asm(short4v a, short4v b, floatx4 c) {
    asm volatile("v_mfma_f32_16x16x16_bf16 %0, %1, %2, %0" : "+v"(c) : "v"(a), "v"(b));
    return c;
}
#  define MFMA16(a, b, c) mfma16_asm(a, b, c)
#endif

// exp2 without the llvm.exp2 denormal-range fixup: scores are bounded
// (|x| < ~40 after LN + QSCALE), so the bare v_exp_f32 is exact here.
// Builtin (not inline asm!) so the compiler inserts TRANS-op wait states.
__device__ __forceinline__ float fexp2(float x) {
#if defined(__has_builtin)
#  if __has_builtin(__builtin_amdgcn_exp2f)
    return __builtin_amdgcn_exp2f(x);
#  else
    return exp2f(x);
#  endif
#else
    return exp2f(x);
#endif
}

// async 16B global -> LDS (DMA; LDS dest is wave-uniform base + lane*16)
__device__ __forceinline__ void gload16(const void* g, void* l) {
    __builtin_amdgcn_global_load_lds(
        (const __attribute__((address_space(1))) unsigned int*)g,
        (__attribute__((address_space(3))) unsigned int*)l,
        16, 0, 0);
}

#define QSCALE 0.18033688011112042f   // 0.125 * log2(e), pre-applied to Q

// ---------------------------------------------------------------------------
// One-shot bf16 cast of x and the four weight matrices. (R9-exact form.)
// ---------------------------------------------------------------------------
__global__ __launch_bounds__(256) void cast_all(
    const float* __restrict__ x,
    const float* __restrict__ Wq, const float* __restrict__ Wk,
    const float* __restrict__ Wv, const float* __restrict__ Wp,
    short* __restrict__ xh, short* __restrict__ Wqh, short* __restrict__ Wkh,
    short* __restrict__ Wvh, short* __restrict__ Wph)
{
    const float* src; short* dst; int n4;
    switch (blockIdx.y) {
        case 0:  src = x;  dst = xh;  n4 = (Bb * Nn * Dd) / 4; break;
        case 1:  src = Wq; dst = Wqh; n4 = (Dd * Dd) / 4; break;
        case 2:  src = Wk; dst = Wkh; n4 = (Dd * Dd) / 4; break;
        case 3:  src = Wv; dst = Wvh; n4 = (Dd * Dd) / 4; break;
        default: src = Wp; dst = Wph; n4 = (Dd * Dd) / 4; break;
    }
    const int i = blockIdx.x * 256 + threadIdx.x;
    if (i >= n4) return;
    float4 v = ((const float4*)src)[i];
    short4v o;
    o.x = f2bf(v.x); o.y = f2bf(v.y); o.z = f2bf(v.z); o.w = f2bf(v.w);
    ((short4v*)dst)[i] = o;
}

// ---------------------------------------------------------------------------
// Fused QKV GEMM with per-head LayerNorm epilogue. Verified R7/R9 form:
// BK=64 via twin [128][32] LDS buffers, NATURAL dispatch order. Measured
// closures: ping-pong (R8, 81.9us) and XCD panel-swizzle (R14, FETCH 33->69MB:
// natural stride-32 ids already put A-row-sharing blocks on one XCD; the
// panel remap destroyed A-locality to chase the smaller W working set).
// ---------------------------------------------------------------------------
__global__ __launch_bounds__(256) void qkv_ln_gemm(
    const short* __restrict__ xh,
    const short* __restrict__ Wqh, const short* __restrict__ Wkh,
    const short* __restrict__ Wvh,
    const float* __restrict__ bq, const float* __restrict__ bk,
    const float* __restrict__ bv,
    const float* __restrict__ qg, const float* __restrict__ qb,
    const float* __restrict__ kg, const float* __restrict__ kb,
    short* __restrict__ Qh, short* __restrict__ Kh, short* __restrict__ Vt)
{
    const int z = blockIdx.z;
    const short* A; const short* W;
    int rowBase, colBase, Nc;
    if (z < 2) { A = xh;  W = z ? Wkh : Wqh;
                 rowBase = blockIdx.x * 128; colBase = blockIdx.y * 128; Nc = Dd; }
    else       { A = Wvh; W = xh;
                 rowBase = blockIdx.y * 128; colBase = blockIdx.x * 128; Nc = Bb * Nn; }

    __shared__ __align__(16) short As0[128 * 32];
    __shared__ __align__(16) short As1[128 * 32];
    __shared__ __align__(16) short Ws0[128 * 32];
    __shared__ __align__(16) short Ws1[128 * 32];

    const int t    = threadIdx.x;
    const int w    = t >> 6;
    const int lane = t & 63;
    const int quad = lane >> 4;
    const int l15  = lane & 15;
    const int wy   = w >> 1;
    const int wx   = w & 1;

    const int r0 = t >> 2;
    const int kg4 = (t & 3) * 8;
    const short* aP = A + (size_t)(rowBase + r0) * Dd + kg4;
    const short* wP = W + (size_t)(colBase + r0) * Dd + kg4;
    const size_t rowskip = (size_t)64 * Dd;

    floatx4 acc[4][4];
    #pragma unroll
    for (int mi = 0; mi < 4; ++mi)
        #pragma unroll
        for (int ni = 0; ni < 4; ++ni)
            acc[mi][ni] = (floatx4){0.f, 0.f, 0.f, 0.f};

    for (int k0 = 0; k0 < Dd; k0 += 64) {
        gload16(aP,                &As0[t * 8]);
        gload16(aP + rowskip,      &As0[(t + 256) * 8]);
        gload16(aP + 32,           &As1[t * 8]);
        gload16(aP + rowskip + 32, &As1[(t + 256) * 8]);
        gload16(wP,                &Ws0[t * 8]);
        gload16(wP + rowskip,      &Ws0[(t + 256) * 8]);
        gload16(wP + 32,           &Ws1[t * 8]);
        gload16(wP + rowskip + 32, &Ws1[(t + 256) * 8]);
        aP += 64; wP += 64;
        __syncthreads();   // drains vmcnt -> staged tiles visible

        #pragma unroll
        for (int ks = 0; ks < 2; ++ks) {
            const short* Ab = ks ? As1 : As0;
            const short* Wb = ks ? Ws1 : Ws0;
            short8 af[4], bfr[4];
            #pragma unroll
            for (int i = 0; i < 4; ++i) {
                af[i]  = *(const short8*)&Ab[(wy * 64 + i * 16 + l15) * 32 + quad * 8];
                bfr[i] = *(const short8*)&Wb[(wx * 64 + i * 16 + l15) * 32 + quad * 8];
            }
            #pragma unroll
            for (int mi = 0; mi < 4; ++mi)
                #pragma unroll
                for (int ni = 0; ni < 4; ++ni)
                    acc[mi][ni] = __builtin_amdgcn_mfma_f32_16x16x32_bf16(
                        af[mi], bfr[ni], acc[mi][ni], 0, 0, 0);
        }
        __syncthreads();
    }

    if (z == 2) {
        #pragma unroll
        for (int mi = 0; mi < 4; ++mi) {
            #pragma unroll
            for (int r = 0; r < 4; ++r) {
                const size_t row = rowBase + wy * 64 + mi * 16 + quad * 4 + r;
                const float brv = bv[row];
                #pragma unroll
                for (int ni = 0; ni < 4; ++ni) {
                    const int col = colBase + wx * 64 + ni * 16 + l15;
                    Vt[row * (size_t)Nc + col] = f2bf(acc[mi][ni][r] + brv);
                }
            }
        }
    } else {
        const float* bias = z ? bk : bq;
        const float* gam  = z ? kg : qg;
        const float* bet  = z ? kb : qb;
        const float oscale = z ? 1.0f : QSCALE;
        short* out = z ? Kh : Qh;
        float bcol[4], g4[4], be4[4];
        #pragma unroll
        for (int ni = 0; ni < 4; ++ni) {
            const int ch = ni * 16 + l15;
            bcol[ni] = bias[colBase + wx * 64 + ch];
            g4[ni]   = gam[ch];
            be4[ni]  = bet[ch];
        }
        #pragma unroll
        for (int mi = 0; mi < 4; ++mi) {
            #pragma unroll
            for (int r = 0; r < 4; ++r) {
                const size_t row = rowBase + wy * 64 + mi * 16 + quad * 4 + r;
                float v[4], s = 0.f, s2 = 0.f;
                #pragma unroll
                for (int ni = 0; ni < 4; ++ni) {
                    v[ni] = acc[mi][ni][r] + bcol[ni];
                    s += v[ni]; s2 += v[ni] * v[ni];
                }
                #pragma unroll
                for (int d = 1; d < 16; d <<= 1) {
                    s  += __shfl_xor(s,  d, 16);
                    s2 += __shfl_xor(s2, d, 16);
                }
                const float mean = s * (1.0f / 64.0f);
                const float var  = s2 * (1.0f / 64.0f) - mean * mean;   // biased (jnp.var)
                const float rr   = rsqrtf(var + 1e-5f);
                #pragma unroll
                for (int ni = 0; ni < 4; ++ni) {
                    const int col = colBase + wx * 64 + ni * 16 + l15;
                    out[row * (size_t)Dd + col] =
                        f2bf(((v[ni] - mean) * rr * g4[ni] + be4[ni]) * oscale);
                }
            }
        }
    }
}

// ---------------------------------------------------------------------------
// Output projection GEMM. Verified R7/R9 form: BK=64 twin buffers,
// 128x64 tile, 512 blocks = 2/CU. (Ping-pong measured -6us here in R12.)
// ---------------------------------------------------------------------------
__global__ __launch_bounds__(256) void gemm_mfma(
    const short* __restrict__ A, const short* __restrict__ W,
    const float* __restrict__ bias, float* __restrict__ Cf,
    int M, int K, int Nc)
{
    __shared__ __align__(16) short As0[128 * 32];   // 8 KB
    __shared__ __align__(16) short As1[128 * 32];   // 8 KB
    __shared__ __align__(16) short Ws0[64 * 32];    // 4 KB
    __shared__ __align__(16) short Ws1[64 * 32];    // 4 KB

    const int t    = threadIdx.x;
    const int w    = t >> 6;
    const int lane = t & 63;
    const int quad = lane >> 4;
    const int l15  = lane & 15;
    const int wy   = w >> 1;
    const int wx   = w & 1;
    const int rowBase = blockIdx.y * 128;
    const int colBase = blockIdx.x * 64;

    const int r0 = t >> 2;          // 0..63
    const int kg4 = (t & 3) * 8;
    const short* aP = A + (size_t)(rowBase + r0) * K + kg4;
    const short* wP = W + (size_t)(colBase + r0) * K + kg4;
    const size_t rowskip = (size_t)64 * K;

    floatx4 acc[4][2];
    #pragma unroll
    for (int mi = 0; mi < 4; ++mi)
        #pragma unroll
        for (int ni = 0; ni < 2; ++ni)
            acc[mi][ni] = (floatx4){0.f, 0.f, 0.f, 0.f};

    for (int k0 = 0; k0 < K; k0 += 64) {
        gload16(aP,                &As0[t * 8]);
        gload16(aP + rowskip,      &As0[(t + 256) * 8]);
        gload16(aP + 32,           &As1[t * 8]);
        gload16(aP + rowskip + 32, &As1[(t + 256) * 8]);
        gload16(wP,                &Ws0[t * 8]);
        gload16(wP + 32,           &Ws1[t * 8]);
        aP += 64; wP += 64;
        __syncthreads();

        #pragma unroll
        for (int ks = 0; ks < 2; ++ks) {
            const short* Ab = ks ? As1 : As0;
            const short* Wb = ks ? Ws1 : Ws0;
            short8 af[4], bfr[2];
            #pragma unroll
            for (int i = 0; i < 4; ++i)
                af[i]  = *(const short8*)&Ab[(wy * 64 + i * 16 + l15) * 32 + quad * 8];
            #pragma unroll
            for (int i = 0; i < 2; ++i)
                bfr[i] = *(const short8*)&Wb[(wx * 32 + i * 16 + l15) * 32 + quad * 8];
            #pragma unroll
            for (int mi = 0; mi < 4; ++mi)
                #pragma unroll
                for (int ni = 0; ni < 2; ++ni)
                    acc[mi][ni] = __builtin_amdgcn_mfma_f32_16x16x32_bf16(
                        af[mi], bfr[ni], acc[mi][ni], 0, 0, 0);
        }
        __syncthreads();
    }

    #pragma unroll
    for (int mi = 0; mi < 4; ++mi) {
        #pragma unroll
        for (int r = 0; r < 4; ++r) {
            const size_t row = rowBase + wy * 64 + mi * 16 + quad * 4 + r;
            #pragma unroll
            for (int ni = 0; ni < 2; ++ni) {
                const int col = colBase + wx * 32 + ni * 16 + l15;
                Cf[row * Nc + col] = acc[mi][ni][r] + bias[col];
            }
        }
    }
}

// ---------------------------------------------------------------------------
// Flash attention, bf16 MFMA, static-max softmax. Verified R9 form (52.7us):
// KVB=128, 512 threads, XCD group-swizzle (FETCH 73.7->12.8MB), builtin exp2,
// setprio, conflict-free K/V LDS strides. Residual SQ_LDS_BANK_CONFLICT =
// 2^22 exactly = benign 2-way alias on K b128 reads (l15 vs l15+8), ~free.
// ---------------------------------------------------------------------------
__global__ __launch_bounds__(512, 4) void flash_mfma(
    const short* __restrict__ Qh, const short* __restrict__ Kh,
    const short* __restrict__ Vt, short* __restrict__ ctx)
{
    // ---- XCD group-swizzle (bijective on 0..511) ----
    const int lin = blockIdx.x + (blockIdx.y << 4) + (blockIdx.z << 8);
    const int xcd = lin & 7;          // dispatcher round-robins linear id % 8
    const int ixc = lin >> 3;         // 0..63 within this XCD
    const int grp = xcd * 4 + (ixc >> 4);   // 0..31 = (h,b) group, 4 per XCD
    const int qt  = ixc & 15;         // 128-query tile
    const int h   = grp & 15;
    const int b   = grp >> 4;

    const int t    = threadIdx.x;   // 0..511
    const int w    = t >> 6;        // wave 0..7
    const int lane = t & 63;
    const int quad = lane >> 4;
    const int l15  = lane & 15;

    __shared__ __align__(16) short Ksh[KVB][72];   // [key][d]  18432B (stride 144B: clean b128)
    __shared__ __align__(16) short Vsh[64][140];   // [ch][key] 17920B (stride 280B = 70 dw == 6 mod 32: clean b64)

    const size_t bhead = (size_t)b * Nn * Dd + (size_t)h * HD;

    // Q B-frags: one 16-query set per wave, held in registers for all k-tiles
    short8 qf[2];
    {
        const short* qp = Qh + bhead
            + (size_t)(qt * 128 + w * 16 + l15) * Dd + quad * 8;
        qf[0] = *(const short8*)qp;
        qf[1] = *(const short8*)(qp + 32);
    }

    floatx4 accO[4], accL;
    #pragma unroll
    for (int n = 0; n < 4; ++n) accO[n] = (floatx4){0.f, 0.f, 0.f, 0.f};
    accL = (floatx4){0.f, 0.f, 0.f, 0.f};
    short4v ones;
    ones[0] = ones[1] = ones[2] = ones[3] = (short)0x3F80;   // bf16 1.0

    // staging: thread t owns K rows {s3, s3+64} (d-chunk skg) and V channel s3
    // (key chunks {skg, skg+64}); chunk rotated per row to spread banks.
    const int s3  = t >> 3;                   // 0..63
    const int c3  = ((t & 7) + (s3 & 7)) & 7;
    const int skg = c3 * 8;
    const short* kP = Kh + bhead + (size_t)s3 * Dd + skg;
    const short* vP = Vt + (size_t)(h * 64 + s3) * (size_t)(Bb * Nn) + (size_t)b * Nn + skg;

    // prefetch tile 0 into registers
    short8 kr0 = *(const short8*)kP;
    short8 kr1 = *(const short8*)(kP + (size_t)64 * Dd);
    short8 vr0 = *(const short8*)vP;
    short8 vr1 = *(const short8*)(vP + 64);

    for (int k0 = 0; k0 < Nn; k0 += KVB) {
        // ---- write prefetched tile to LDS ----
        *(short8*)&Ksh[s3][skg]      = kr0;
        *(short8*)&Ksh[s3 + 64][skg] = kr1;
        {   // V rows are 8B-aligned (stride 280B): write as b64 halves
            union { short8 v8; short4v v4[2]; } a0, a1;
            a0.v8 = vr0; a1.v8 = vr1;
            *(short4v*)&Vsh[s3][skg]      = a0.v4[0];
            *(short4v*)&Vsh[s3][skg + 4]  = a0.v4[1];
            *(short4v*)&Vsh[s3][skg + 64] = a1.v4[0];
            *(short4v*)&Vsh[s3][skg + 68] = a1.v4[1];
        }
        __syncthreads();   // staged tile visible to all waves

        // ---- issue next tile's global loads (hidden behind compute) ----
        kP += (size_t)KVB * Dd; vP += KVB;   // last iter strays into d_ws (safe, unused)
        kr0 = *(const short8*)kP;
        kr1 = *(const short8*)(kP + (size_t)64 * Dd);
        vr0 = *(const short8*)vP;
        vr1 = *(const short8*)(vP + 64);

        // ---- per 16-key subtile: S^T = K Q^T -> exp2 -> pack -> l, O += P V
        __builtin_amdgcn_s_setprio(1);
        #pragma unroll
        for (int n = 0; n < KVB / 16; ++n) {
            short8 kf0 = *(const short8*)&Ksh[n * 16 + l15][quad * 8];
            short8 kf1 = *(const short8*)&Ksh[n * 16 + l15][32 + quad * 8];
            floatx4 zz = (floatx4){0.f, 0.f, 0.f, 0.f};
            zz = __builtin_amdgcn_mfma_f32_16x16x32_bf16(kf0, qf[0], zz, 0, 0, 0);
            zz = __builtin_amdgcn_mfma_f32_16x16x32_bf16(kf1, qf[1], zz, 0, 0, 0);

            const unsigned u0 = __float_as_uint(fexp2(zz[0]));
            const unsigned u1 = __float_as_uint(fexp2(zz[1]));
            const unsigned u2 = __float_as_uint(fexp2(zz[2]));
            const unsigned u3 = __float_as_uint(fexp2(zz[3]));
            union { uint2 u; short4v s; } pk;
            pk.u.x = __builtin_amdgcn_perm(u1, u0, 0x07060302u);  // trunc-bf16 pair
            pk.u.y = __builtin_amdgcn_perm(u3, u2, 0x07060302u);
            accL = MFMA16(pk.s, ones, accL);   // l += P·1 (matrix pipe)

            #pragma unroll
            for (int c = 0; c < 4; ++c) {   // channel subtile
                const short4v vb =
                    *(const short4v*)&Vsh[c * 16 + l15][n * 16 + quad * 4];
                accO[c] = MFMA16(pk.s, vb, accO[c]);
            }
        }
        __builtin_amdgcn_s_setprio(0);
        __syncthreads();   // protect Ksh/Vsh before next tile's LDS write
    }

    // ---- epilogue: accL[r] IS this lane's query's l -> normalize ----
    #pragma unroll
    for (int r = 0; r < 4; ++r) {
        const float lr = 1.0f / accL[r];
        short* dst = ctx + (size_t)((b * Nn) + qt * 128 + w * 16
                                    + quad * 4 + r) * Dd + h * HD + l15;
        #pragma unroll
        for (int n = 0; n < 4; ++n) dst[n * 16] = f2bf(accO[n][r] * lr);
    }
}

// ---------------------------------------------------------------------------
extern "C" void kernel_launch(void* const* d_in, const int* in_sizes, int n_in,
                              void* d_out, int out_size, void* d_ws, size_t ws_size,
                              hipStream_t stream) {
    const float* x   = (const float*)d_in[0];
    const float* Wq  = (const float*)d_in[1];
    const float* bq  = (const float*)d_in[2];
    const float* Wk  = (const float*)d_in[3];
    const float* bk  = (const float*)d_in[4];
    const float* Wv  = (const float*)d_in[5];
    const float* bv  = (const float*)d_in[6];
    const float* Wp  = (const float*)d_in[7];
    const float* bp  = (const float*)d_in[8];
    const float* qg  = (const float*)d_in[9];
    const float* qb  = (const float*)d_in[10];
    const float* kg  = (const float*)d_in[11];
    const float* kb  = (const float*)d_in[12];
    float* out = (float*)d_out;

    const size_t S = (size_t)Bb * Nn * Dd;   // 4,194,304 elements
    short* wsb = (short*)d_ws;               // all-bf16 workspace (48 MB)
    short* xh   = wsb;                       // [0,  8MB)
    short* Vt   = wsb + S;                   // [8, 16MB)  V^T [1024][4096]
    short* Kh   = wsb + 2 * S;               // [16,24MB)
    short* Qh   = wsb + 3 * S;               // [24,32MB)
    short* ctxh = wsb + 4 * S;               // [32,40MB)
    short* Wqh  = wsb + 5 * S;               // [40,48MB) 4 weights, 2MB each
    short* Wkh  = Wqh + Dd * Dd;
    short* Wvh  = Wkh + Dd * Dd;
    short* Wph  = Wvh + Dd * Dd;

    const int M = Bb * Nn;                   // 4096

    cast_all<<<dim3(4096, 5), 256, 0, stream>>>(x, Wq, Wk, Wv, Wp,
                                                xh, Wqh, Wkh, Wvh, Wph);

    // fused QKV projections + per-head LN (Q,K; Q pre-scaled) + transposed V
    qkv_ln_gemm<<<dim3(M / 128, Dd / 128, 3), 256, 0, stream>>>(
        xh, Wqh, Wkh, Wvh, bq, bk, bv, qg, qb, kg, kb, Qh, Kh, Vt);

    flash_mfma<<<dim3(Nn / 128, Hh, Bb), 512, 0, stream>>>(Qh, Kh, Vt, ctxh);

    // output projection (bf16 MFMA, fp32 out + bias): twin-buffer BK=64
    gemm_mfma<<<dim3(Dd / 64, M / 128, 1), 256, 0, stream>>>(
        ctxh, Wph, bp, out, M, Dd, Dd);
}

// Round 17
// 196.735 us; speedup vs baseline: 1.0642x; 1.0316x over previous
//
#include <hip/hip_runtime.h>
#include <math.h>

#define Bb 2
#define Nn 2048
#define Dd 1024
#define Hh 16
#define HD 64
#define KVB 128
// M = B*N = 4096 rows

typedef __attribute__((ext_vector_type(8))) short short8;    // 8 bf16 = 4 VGPR (MFMA A/B frag)
typedef __attribute__((ext_vector_type(4))) short short4v;   // 4 bf16 = 2 VGPR (K=16 MFMA frag)
typedef __attribute__((ext_vector_type(4))) float floatx4;   // MFMA C/D frag

// float -> bf16 bits, round-to-nearest-even (values are finite here)
__device__ __forceinline__ short f2bf(float x) {
    unsigned u = __float_as_uint(x);
    u += 0x7fffu + ((u >> 16) & 1u);
    return (short)(u >> 16);
}

// K=16 bf16 MFMA: A-frag layout A[m=lane&15][k=quad*4+j] == C/D layout of the
// S-MFMA -> P feeds PV directly from accumulator registers (no LDS roundtrip).
#if defined(__has_builtin)
#  if __has_builtin(__builtin_amdgcn_mfma_f32_16x16x16bf16_1k)
#    define MFMA16(a, b, c) __builtin_amdgcn_mfma_f32_16x16x16bf16_1k(a, b, c, 0, 0, 0)
#  endif
#endif
#ifndef MFMA16
static __device__ __forceinline__ floatx4 mfma16_asm(short4v a, short4v b, floatx4 c) {
    asm volatile("v_mfma_f32_16x16x16_bf16 %0, %1, %2, %0" : "+v"(c) : "v"(a), "v"(b));
    return c;
}
#  define MFMA16(a, b, c) mfma16_asm(a, b, c)
#endif

// exp2 without the llvm.exp2 denormal-range fixup: scores are bounded
// (|x| < ~40 after LN + QSCALE), so the bare v_exp_f32 is exact here.
// Builtin (not inline asm!) so the compiler inserts TRANS-op wait states.
__device__ __forceinline__ float fexp2(float x) {
#if defined(__has_builtin)
#  if __has_builtin(__builtin_amdgcn_exp2f)
    return __builtin_amdgcn_exp2f(x);
#  else
    return exp2f(x);
#  endif
#else
    return exp2f(x);
#endif
}

// async 16B global -> LDS (DMA; LDS dest is wave-uniform base + lane*16)
__device__ __forceinline__ void gload16(const void* g, void* l) {
    __builtin_amdgcn_global_load_lds(
        (const __attribute__((address_space(1))) unsigned int*)g,
        (__attribute__((address_space(3))) unsigned int*)l,
        16, 0, 0);
}

#define QSCALE 0.18033688011112042f   // 0.125 * log2(e), pre-applied to Q

// ---------------------------------------------------------------------------
// One-shot bf16 cast of x and the four weight matrices. (R9-exact form.)
// ---------------------------------------------------------------------------
__global__ __launch_bounds__(256) void cast_all(
    const float* __restrict__ x,
    const float* __restrict__ Wq, const float* __restrict__ Wk,
    const float* __restrict__ Wv, const float* __restrict__ Wp,
    short* __restrict__ xh, short* __restrict__ Wqh, short* __restrict__ Wkh,
    short* __restrict__ Wvh, short* __restrict__ Wph)
{
    const float* src; short* dst; int n4;
    switch (blockIdx.y) {
        case 0:  src = x;  dst = xh;  n4 = (Bb * Nn * Dd) / 4; break;
        case 1:  src = Wq; dst = Wqh; n4 = (Dd * Dd) / 4; break;
        case 2:  src = Wk; dst = Wkh; n4 = (Dd * Dd) / 4; break;
        case 3:  src = Wv; dst = Wvh; n4 = (Dd * Dd) / 4; break;
        default: src = Wp; dst = Wph; n4 = (Dd * Dd) / 4; break;
    }
    const int i = blockIdx.x * 256 + threadIdx.x;
    if (i >= n4) return;
    float4 v = ((const float4*)src)[i];
    short4v o;
    o.x = f2bf(v.x); o.y = f2bf(v.y); o.z = f2bf(v.z); o.w = f2bf(v.w);
    ((short4v*)dst)[i] = o;
}

// ---------------------------------------------------------------------------
// Fused QKV GEMM with per-head LayerNorm epilogue. R16: same verified
// twin-buffer BK=64 sync structure, but 512 threads / 8 waves per block
// (wave does 32x64, acc[2][4]) -> 24 waves/CU ceiling vs 12. Per-element
// K-accumulation order identical; barriers unchanged; staging simplifies to
// 4 gloads/thread/K-step (r0 = t>>2 spans all 128 rows directly).
// Closed levers: ping-pong (R8, +29us), XCD panel-swizzle (R14, FETCH 2x).
// ---------------------------------------------------------------------------
__global__ __launch_bounds__(512, 4) void qkv_ln_gemm(
    const short* __restrict__ xh,
    const short* __restrict__ Wqh, const short* __restrict__ Wkh,
    const short* __restrict__ Wvh,
    const float* __restrict__ bq, const float* __restrict__ bk,
    const float* __restrict__ bv,
    const float* __restrict__ qg, const float* __restrict__ qb,
    const float* __restrict__ kg, const float* __restrict__ kb,
    short* __restrict__ Qh, short* __restrict__ Kh, short* __restrict__ Vt)
{
    const int z = blockIdx.z;
    const short* A; const short* W;
    int rowBase, colBase, Nc;
    if (z < 2) { A = xh;  W = z ? Wkh : Wqh;
                 rowBase = blockIdx.x * 128; colBase = blockIdx.y * 128; Nc = Dd; }
    else       { A = Wvh; W = xh;
                 rowBase = blockIdx.y * 128; colBase = blockIdx.x * 128; Nc = Bb * Nn; }

    __shared__ __align__(16) short As0[128 * 32];
    __shared__ __align__(16) short As1[128 * 32];
    __shared__ __align__(16) short Ws0[128 * 32];
    __shared__ __align__(16) short Ws1[128 * 32];

    const int t    = threadIdx.x;   // 0..511
    const int w    = t >> 6;        // wave 0..7
    const int lane = t & 63;
    const int quad = lane >> 4;
    const int l15  = lane & 15;
    const int wy   = w >> 1;        // 0..3: 32-row band
    const int wx   = w & 1;         // 0..1: 64-col half

    const int r0 = t >> 2;          // 0..127 (all 128 tile rows)
    const int kg4 = (t & 3) * 8;
    const short* aP = A + (size_t)(rowBase + r0) * Dd + kg4;
    const short* wP = W + (size_t)(colBase + r0) * Dd + kg4;

    floatx4 acc[2][4];
    #pragma unroll
    for (int mi = 0; mi < 2; ++mi)
        #pragma unroll
        for (int ni = 0; ni < 4; ++ni)
            acc[mi][ni] = (floatx4){0.f, 0.f, 0.f, 0.f};

    for (int k0 = 0; k0 < Dd; k0 += 64) {
        gload16(aP,      &As0[t * 8]);
        gload16(aP + 32, &As1[t * 8]);
        gload16(wP,      &Ws0[t * 8]);
        gload16(wP + 32, &Ws1[t * 8]);
        aP += 64; wP += 64;
        __syncthreads();   // drains vmcnt -> staged tiles visible

        #pragma unroll
        for (int ks = 0; ks < 2; ++ks) {
            const short* Ab = ks ? As1 : As0;
            const short* Wb = ks ? Ws1 : Ws0;
            short8 af[2], bfr[4];
            #pragma unroll
            for (int i = 0; i < 2; ++i)
                af[i]  = *(const short8*)&Ab[(wy * 32 + i * 16 + l15) * 32 + quad * 8];
            #pragma unroll
            for (int i = 0; i < 4; ++i)
                bfr[i] = *(const short8*)&Wb[(wx * 64 + i * 16 + l15) * 32 + quad * 8];
            #pragma unroll
            for (int mi = 0; mi < 2; ++mi)
                #pragma unroll
                for (int ni = 0; ni < 4; ++ni)
                    acc[mi][ni] = __builtin_amdgcn_mfma_f32_16x16x32_bf16(
                        af[mi], bfr[ni], acc[mi][ni], 0, 0, 0);
        }
        __syncthreads();
    }

    if (z == 2) {
        #pragma unroll
        for (int mi = 0; mi < 2; ++mi) {
            #pragma unroll
            for (int r = 0; r < 4; ++r) {
                const size_t row = rowBase + wy * 32 + mi * 16 + quad * 4 + r;
                const float brv = bv[row];
                #pragma unroll
                for (int ni = 0; ni < 4; ++ni) {
                    const int col = colBase + wx * 64 + ni * 16 + l15;
                    Vt[row * (size_t)Nc + col] = f2bf(acc[mi][ni][r] + brv);
                }
            }
        }
    } else {
        const float* bias = z ? bk : bq;
        const float* gam  = z ? kg : qg;
        const float* bet  = z ? kb : qb;
        const float oscale = z ? 1.0f : QSCALE;
        short* out = z ? Kh : Qh;
        float bcol[4], g4[4], be4[4];
        #pragma unroll
        for (int ni = 0; ni < 4; ++ni) {
            const int ch = ni * 16 + l15;
            bcol[ni] = bias[colBase + wx * 64 + ch];
            g4[ni]   = gam[ch];
            be4[ni]  = bet[ch];
        }
        #pragma unroll
        for (int mi = 0; mi < 2; ++mi) {
            #pragma unroll
            for (int r = 0; r < 4; ++r) {
                const size_t row = rowBase + wy * 32 + mi * 16 + quad * 4 + r;
                float v[4], s = 0.f, s2 = 0.f;
                #pragma unroll
                for (int ni = 0; ni < 4; ++ni) {
                    v[ni] = acc[mi][ni][r] + bcol[ni];
                    s += v[ni]; s2 += v[ni] * v[ni];
                }
                #pragma unroll
                for (int d = 1; d < 16; d <<= 1) {
                    s  += __shfl_xor(s,  d, 16);
                    s2 += __shfl_xor(s2, d, 16);
                }
                const float mean = s * (1.0f / 64.0f);
                const float var  = s2 * (1.0f / 64.0f) - mean * mean;   // biased (jnp.var)
                const float rr   = rsqrtf(var + 1e-5f);
                #pragma unroll
                for (int ni = 0; ni < 4; ++ni) {
                    const int col = colBase + wx * 64 + ni * 16 + l15;
                    out[row * (size_t)Dd + col] =
                        f2bf(((v[ni] - mean) * rr * g4[ni] + be4[ni]) * oscale);
                }
            }
        }
    }
}

// ---------------------------------------------------------------------------
// Output projection GEMM. R16: twin-buffer BK=64 structure, 512 threads /
// 8 waves (wave does 32x32, acc[2][2]) -> 16 waves/CU vs 8. W (64 rows per
// buffer) staged by thread halves: t<256 -> Ws0, t>=256 -> Ws1 (wave-uniform
// LDS bases). Per-element accumulation order identical.
// ---------------------------------------------------------------------------
__global__ __launch_bounds__(512, 4) void gemm_mfma(
    const short* __restrict__ A, const short* __restrict__ W,
    const float* __restrict__ bias, float* __restrict__ Cf,
    int M, int K, int Nc)
{
    __shared__ __align__(16) short As0[128 * 32];   // 8 KB
    __shared__ __align__(16) short As1[128 * 32];   // 8 KB
    __shared__ __align__(16) short Ws0[64 * 32];    // 4 KB
    __shared__ __align__(16) short Ws1[64 * 32];    // 4 KB

    const int t    = threadIdx.x;   // 0..511
    const int w    = t >> 6;        // wave 0..7
    const int lane = t & 63;
    const int quad = lane >> 4;
    const int l15  = lane & 15;
    const int wy   = w >> 1;        // 0..3: 32-row band
    const int wx   = w & 1;         // 0..1: 32-col half
    const int rowBase = blockIdx.y * 128;
    const int colBase = blockIdx.x * 64;

    const int r0 = t >> 2;          // 0..127 (all A rows)
    const int kg4 = (t & 3) * 8;
    const short* aP = A + (size_t)(rowBase + r0) * K + kg4;

    const int tw = t & 255;         // W staging: halves cover Ws0 / Ws1
    const int rw = tw >> 2;         // 0..63
    const int kw = (tw & 3) * 8;
    const short* wP = W + (size_t)(colBase + rw) * K + kw + (t >= 256 ? 32 : 0);
    short* wdst = ((t < 256) ? Ws0 : Ws1) + tw * 8;   // wave-uniform base

    floatx4 acc[2][2];
    #pragma unroll
    for (int mi = 0; mi < 2; ++mi)
        #pragma unroll
        for (int ni = 0; ni < 2; ++ni)
            acc[mi][ni] = (floatx4){0.f, 0.f, 0.f, 0.f};

    for (int k0 = 0; k0 < K; k0 += 64) {
        gload16(aP,      &As0[t * 8]);
        gload16(aP + 32, &As1[t * 8]);
        gload16(wP,      wdst);
        aP += 64; wP += 64;
        __syncthreads();

        #pragma unroll
        for (int ks = 0; ks < 2; ++ks) {
            const short* Ab = ks ? As1 : As0;
            const short* Wb = ks ? Ws1 : Ws0;
            short8 af[2], bfr[2];
            #pragma unroll
            for (int i = 0; i < 2; ++i)
                af[i]  = *(const short8*)&Ab[(wy * 32 + i * 16 + l15) * 32 + quad * 8];
            #pragma unroll
            for (int i = 0; i < 2; ++i)
                bfr[i] = *(const short8*)&Wb[(wx * 32 + i * 16 + l15) * 32 + quad * 8];
            #pragma unroll
            for (int mi = 0; mi < 2; ++mi)
                #pragma unroll
                for (int ni = 0; ni < 2; ++ni)
                    acc[mi][ni] = __builtin_amdgcn_mfma_f32_16x16x32_bf16(
                        af[mi], bfr[ni], acc[mi][ni], 0, 0, 0);
        }
        __syncthreads();
    }

    #pragma unroll
    for (int mi = 0; mi < 2; ++mi) {
        #pragma unroll
        for (int r = 0; r < 4; ++r) {
            const size_t row = rowBase + wy * 32 + mi * 16 + quad * 4 + r;
            #pragma unroll
            for (int ni = 0; ni < 2; ++ni) {
                const int col = colBase + wx * 32 + ni * 16 + l15;
                Cf[row * Nc + col] = acc[mi][ni][r] + bias[col];
            }
        }
    }
}

// ---------------------------------------------------------------------------
// Flash attention, bf16 MFMA, static-max softmax. Verified R9/R15 form
// (52us): KVB=128, 512 threads, XCD group-swizzle (FETCH 12.8MB), builtin
// exp2, setprio, conflict-free K/V LDS strides. Residual bank-conflict
// counter = 2^22 exactly = benign 2-way alias on K b128 reads, ~free.
// ---------------------------------------------------------------------------
__global__ __launch_bounds__(512, 4) void flash_mfma(
    const short* __restrict__ Qh, const short* __restrict__ Kh,
    const short* __restrict__ Vt, short* __restrict__ ctx)
{
    // ---- XCD group-swizzle (bijective on 0..511) ----
    const int lin = blockIdx.x + (blockIdx.y << 4) + (blockIdx.z << 8);
    const int xcd = lin & 7;          // dispatcher round-robins linear id % 8
    const int ixc = lin >> 3;         // 0..63 within this XCD
    const int grp = xcd * 4 + (ixc >> 4);   // 0..31 = (h,b) group, 4 per XCD
    const int qt  = ixc & 15;         // 128-query tile
    const int h   = grp & 15;
    const int b   = grp >> 4;

    const int t    = threadIdx.x;   // 0..511
    const int w    = t >> 6;        // wave 0..7
    const int lane = t & 63;
    const int quad = lane >> 4;
    const int l15  = lane & 15;

    __shared__ __align__(16) short Ksh[KVB][72];   // [key][d]  18432B (stride 144B: clean b128)
    __shared__ __align__(16) short Vsh[64][140];   // [ch][key] 17920B (stride 280B = 70 dw == 6 mod 32: clean b64)

    const size_t bhead = (size_t)b * Nn * Dd + (size_t)h * HD;

    // Q B-frags: one 16-query set per wave, held in registers for all k-tiles
    short8 qf[2];
    {
        const short* qp = Qh + bhead
            + (size_t)(qt * 128 + w * 16 + l15) * Dd + quad * 8;
        qf[0] = *(const short8*)qp;
        qf[1] = *(const short8*)(qp + 32);
    }

    floatx4 accO[4], accL;
    #pragma unroll
    for (int n = 0; n < 4; ++n) accO[n] = (floatx4){0.f, 0.f, 0.f, 0.f};
    accL = (floatx4){0.f, 0.f, 0.f, 0.f};
    short4v ones;
    ones[0] = ones[1] = ones[2] = ones[3] = (short)0x3F80;   // bf16 1.0

    // staging: thread t owns K rows {s3, s3+64} (d-chunk skg) and V channel s3
    // (key chunks {skg, skg+64}); chunk rotated per row to spread banks.
    const int s3  = t >> 3;                   // 0..63
    const int c3  = ((t & 7) + (s3 & 7)) & 7;
    const int skg = c3 * 8;
    const short* kP = Kh + bhead + (size_t)s3 * Dd + skg;
    const short* vP = Vt + (size_t)(h * 64 + s3) * (size_t)(Bb * Nn) + (size_t)b * Nn + skg;

    // prefetch tile 0 into registers
    short8 kr0 = *(const short8*)kP;
    short8 kr1 = *(const short8*)(kP + (size_t)64 * Dd);
    short8 vr0 = *(const short8*)vP;
    short8 vr1 = *(const short8*)(vP + 64);

    for (int k0 = 0; k0 < Nn; k0 += KVB) {
        // ---- write prefetched tile to LDS ----
        *(short8*)&Ksh[s3][skg]      = kr0;
        *(short8*)&Ksh[s3 + 64][skg] = kr1;
        {   // V rows are 8B-aligned (stride 280B): write as b64 halves
            union { short8 v8; short4v v4[2]; } a0, a1;
            a0.v8 = vr0; a1.v8 = vr1;
            *(short4v*)&Vsh[s3][skg]      = a0.v4[0];
            *(short4v*)&Vsh[s3][skg + 4]  = a0.v4[1];
            *(short4v*)&Vsh[s3][skg + 64] = a1.v4[0];
            *(short4v*)&Vsh[s3][skg + 68] = a1.v4[1];
        }
        __syncthreads();   // staged tile visible to all waves

        // ---- issue next tile's global loads (hidden behind compute) ----
        kP += (size_t)KVB * Dd; vP += KVB;   // last iter strays into d_ws (safe, unused)
        kr0 = *(const short8*)kP;
        kr1 = *(const short8*)(kP + (size_t)64 * Dd);
        vr0 = *(const short8*)vP;
        vr1 = *(const short8*)(vP + 64);

        // ---- per 16-key subtile: S^T = K Q^T -> exp2 -> pack -> l, O += P V
        __builtin_amdgcn_s_setprio(1);
        #pragma unroll
        for (int n = 0; n < KVB / 16; ++n) {
            short8 kf0 = *(const short8*)&Ksh[n * 16 + l15][quad * 8];
            short8 kf1 = *(const short8*)&Ksh[n * 16 + l15][32 + quad * 8];
            floatx4 zz = (floatx4){0.f, 0.f, 0.f, 0.f};
            zz = __builtin_amdgcn_mfma_f32_16x16x32_bf16(kf0, qf[0], zz, 0, 0, 0);
            zz = __builtin_amdgcn_mfma_f32_16x16x32_bf16(kf1, qf[1], zz, 0, 0, 0);

            const unsigned u0 = __float_as_uint(fexp2(zz[0]));
            const unsigned u1 = __float_as_uint(fexp2(zz[1]));
            const unsigned u2 = __float_as_uint(fexp2(zz[2]));
            const unsigned u3 = __float_as_uint(fexp2(zz[3]));
            union { uint2 u; short4v s; } pk;
            pk.u.x = __builtin_amdgcn_perm(u1, u0, 0x07060302u);  // trunc-bf16 pair
            pk.u.y = __builtin_amdgcn_perm(u3, u2, 0x07060302u);
            accL = MFMA16(pk.s, ones, accL);   // l += P·1 (matrix pipe)

            #pragma unroll
            for (int c = 0; c < 4; ++c) {   // channel subtile
                const short4v vb =
                    *(const short4v*)&Vsh[c * 16 + l15][n * 16 + quad * 4];
                accO[c] = MFMA16(pk.s, vb, accO[c]);
            }
        }
        __builtin_amdgcn_s_setprio(0);
        __syncthreads();   // protect Ksh/Vsh before next tile's LDS write
    }

    // ---- epilogue: accL[r] IS this lane's query's l -> normalize ----
    #pragma unroll
    for (int r = 0; r < 4; ++r) {
        const float lr = 1.0f / accL[r];
        short* dst = ctx + (size_t)((b * Nn) + qt * 128 + w * 16
                                    + quad * 4 + r) * Dd + h * HD + l15;
        #pragma unroll
        for (int n = 0; n < 4; ++n) dst[n * 16] = f2bf(accO[n][r] * lr);
    }
}

// ---------------------------------------------------------------------------
extern "C" void kernel_launch(void* const* d_in, const int* in_sizes, int n_in,
                              void* d_out, int out_size, void* d_ws, size_t ws_size,
                              hipStream_t stream) {
    const float* x   = (const float*)d_in[0];
    const float* Wq  = (const float*)d_in[1];
    const float* bq  = (const float*)d_in[2];
    const float* Wk  = (const float*)d_in[3];
    const float* bk  = (const float*)d_in[4];
    const float* Wv  = (const float*)d_in[5];
    const float* bv  = (const float*)d_in[6];
    const float* Wp  = (const float*)d_in[7];
    const float* bp  = (const float*)d_in[8];
    const float* qg  = (const float*)d_in[9];
    const float* qb  = (const float*)d_in[10];
    const float* kg  = (const float*)d_in[11];
    const float* kb  = (const float*)d_in[12];
    float* out = (float*)d_out;

    const size_t S = (size_t)Bb * Nn * Dd;   // 4,194,304 elements
    short* wsb = (short*)d_ws;               // all-bf16 workspace (48 MB)
    short* xh   = wsb;                       // [0,  8MB)
    short* Vt   = wsb + S;                   // [8, 16MB)  V^T [1024][4096]
    short* Kh   = wsb + 2 * S;               // [16,24MB)
    short* Qh   = wsb + 3 * S;               // [24,32MB)
    short* ctxh = wsb + 4 * S;               // [32,40MB)
    short* Wqh  = wsb + 5 * S;               // [40,48MB) 4 weights, 2MB each
    short* Wkh  = Wqh + Dd * Dd;
    short* Wvh  = Wkh + Dd * Dd;
    short* Wph  = Wvh + Dd * Dd;

    const int M = Bb * Nn;                   // 4096

    cast_all<<<dim3(4096, 5), 256, 0, stream>>>(x, Wq, Wk, Wv, Wp,
                                                xh, Wqh, Wkh, Wvh, Wph);

    // fused QKV projections + per-head LN (Q,K; Q pre-scaled) + transposed V
    qkv_ln_gemm<<<dim3(M / 128, Dd / 128, 3), 512, 0, stream>>>(
        xh, Wqh, Wkh, Wvh, bq, bk, bv, qg, qb, kg, kb, Qh, Kh, Vt);

    flash_mfma<<<dim3(Nn / 128, Hh, Bb), 512, 0, stream>>>(Qh, Kh, Vt, ctxh);

    // output projection (bf16 MFMA, fp32 out + bias): twin-buffer BK=64, 8 waves
    gemm_mfma<<<dim3(Dd / 64, M / 128, 1), 512, 0, stream>>>(
        ctxh, Wph, bp, out, M, Dd, Dd);
}